// Round 18
// baseline (430.508 us; speedup 1.0000x reference)
//
#include <hip/hip_runtime.h>
#include <hip/hip_bf16.h>
#include <stdint.h>

#define TT 2048
#define BB 8
#define DD 1024
#define FF 2048   // 4*H*N
#define HN 512
#define KB_CNT 32         // DD/32 k-blocks
#define ROWB 128          // bytes per (row, k-block) in SPLIT layout (legacy A)
#define MSTRIDE 4096      // bytes per row, split layout
#define BROWB 64          // bytes per (row, k-block) in SINGLE-fp16 layout
#define BSTRIDE 2048      // bytes per row, single layout = KB_CNT*BROWB
#define PF 8              // recurrence pipeline depth (R9-proven floor)

typedef float f32x4 __attribute__((ext_vector_type(4)));
typedef float f32x2 __attribute__((ext_vector_type(2)));
typedef _Float16 h8_t __attribute__((ext_vector_type(8)));

#define CC   2.88539008f    // 2/ln2
#define SQC  1.69864360f    // sqrt(2/ln2)

// ---------- fast math helpers ----------
__device__ __forceinline__ float fexp2(float x){ return __builtin_amdgcn_exp2f(x); }
__device__ __forceinline__ float frcp(float x){ return __builtin_amdgcn_rcpf(x); }
__device__ __forceinline__ float fsqrt_(float x){ return __builtin_amdgcn_sqrtf(x); }
__device__ __forceinline__ float fast_sigmoid(float x){
    return frcp(1.0f + fexp2(-1.44269504f * x));
}

// DPP butterfly add
template<int CTRL>
__device__ __forceinline__ float dppadd(float v){
    int x = __builtin_amdgcn_update_dpp(0, __float_as_int(v), CTRL, 0xf, 0xf, true);
    return v + __int_as_float(x);
}
__device__ __forceinline__ float reduce16(float v){
    v = dppadd<0xB1>(v);   // + lane^1
    v = dppadd<0x4E>(v);   // + lane^2
    v = dppadd<0x141>(v);  // row_half_mirror: + lane^4
    v = dppadd<0x140>(v);  // row_mirror:      + lane^8
    return v;
}

// ---------- split fp32 -> (hi,lo) fp16 (legacy fallback) ----------
__device__ __forceinline__ void split8(const float* f, int4& hi, int4& lo){
    union { _Float16 h[8]; int4 i; } a, c;
    #pragma unroll
    for (int u = 0; u < 8; ++u) {
        _Float16 h = (_Float16)f[u];
        a.h[u] = h;
        c.h[u] = (_Float16)(f[u] - (float)h);
    }
    hi = a.i; lo = c.i;
}
// ---------- fp32 -> single fp16 (8 at a time) ----------
__device__ __forceinline__ int4 cvt8(const float* f){
    union { _Float16 h[8]; int4 i; } a;
    #pragma unroll
    for (int u = 0; u < 8; ++u) a.h[u] = (_Float16)f[u];
    return a.i;
}

// ---------- Weff = [Wk;Wv;Wq;Wb] * W_in, fused concat, 64x64 tiles ----------
__global__ __launch_bounds__(256)
void gemm_f32c(const float* __restrict__ s0, const float* __restrict__ s1,
               const float* __restrict__ s2, const float* __restrict__ s3,
               const float* __restrict__ B, float* __restrict__ C)
{
    __shared__ __align__(16) float As[16][68];
    __shared__ __align__(16) float Bs[16][72];
    const int tid = threadIdx.x;
    const int tx = tid & 15, ty = tid >> 4;
    const int n0 = blockIdx.x * 64, m0 = blockIdx.y * 64;
    float acc[4][4] = {};

    const int arow = tid >> 2, ac4 = (tid & 3) << 2;
    const int f = m0 + arow;
    const float* asrc = ((f < 512) ? s0 : (f < 1024) ? s1 : (f < 1536) ? s2 : s3)
                        + (size_t)(f & 511) * DD + ac4;
    const int bk = tid >> 4, bc = tid & 15;

    for (int k0 = 0; k0 < DD; k0 += 16) {
        float4 av = *(const float4*)(asrc + k0);
        As[ac4+0][arow] = av.x; As[ac4+1][arow] = av.y;
        As[ac4+2][arow] = av.z; As[ac4+3][arow] = av.w;
        float4 bv = *(const float4*)&B[(size_t)(k0 + bk) * DD + n0 + bc * 4];
        int p = bc + (bc >> 3);
        *(float4*)&Bs[bk][p << 2] = bv;
        __syncthreads();
        #pragma unroll
        for (int kk = 0; kk < 16; ++kk) {
            float a[4], b[4];
            *(float4*)&a[0] = *(const float4*)&As[kk][ty * 4];
            int p2 = tx + (tx >> 3);
            *(float4*)&b[0] = *(const float4*)&Bs[kk][p2 << 2];
            #pragma unroll
            for (int i = 0; i < 4; ++i)
                #pragma unroll
                for (int j = 0; j < 4; ++j)
                    acc[i][j] = __builtin_fmaf(a[i], b[j], acc[i][j]);
        }
        __syncthreads();
    }
    #pragma unroll
    for (int ii = 0; ii < 4; ++ii) {
        float4 v;
        v.x = acc[ii][0]; v.y = acc[ii][1]; v.z = acc[ii][2]; v.w = acc[ii][3];
        *(float4*)&C[(size_t)(m0 + ty * 4 + ii) * DD + n0 + tx * 4] = v;
    }
}

// ---------- fp32 -> SINGLE fp16 pre-swizzled (A and B operands) ----------
// layout: [row][kb][slot 0..3][16B], chunk c (8 fp16) at slot c ^ (row&3).
__global__ __launch_bounds__(256)
void wconv2(const float* __restrict__ W, char* __restrict__ out)
{
    int gid = blockIdx.x * 256 + threadIdx.x;
    int n  = gid >> 6;
    int kh = gid & 63;          // 16 floats per thread
    const float* src = W + (size_t)n * DD + kh * 16;
    float f[16];
    *(float4*)&f[0]  = *(const float4*)(src + 0);
    *(float4*)&f[4]  = *(const float4*)(src + 4);
    *(float4*)&f[8]  = *(const float4*)(src + 8);
    *(float4*)&f[12] = *(const float4*)(src + 12);
    int4 h0 = cvt8(&f[0]);
    int4 h1 = cvt8(&f[8]);
    int kb = kh >> 1, c0 = (kh & 1) * 2, rs = n & 3;
    char* dst = out + (size_t)n * BSTRIDE + kb * BROWB;
    *(int4*)(dst + (((c0+0) ^ rs) * 16)) = h0;
    *(int4*)(dst + (((c0+1) ^ rs) * 16)) = h1;
}

// Epilogue packet layout (8192B per row m, 512B per h), de-interleaved:
//   k@0 + idx*4, q@128 + idx*4, v~@256 + idx*4 (SQC*v), b~@384 + idx*4
#define EPI_STORE(Cb, rbase, reg, hh, idx, blk, v, bb) { \
    char* rowp = (char*)(Cb) + (size_t)((rbase) + (reg)) * 8192 + (hh) * 512; \
    int sub_ = ((blk) == 0) ? 0 : ((blk) == 2) ? 1 : ((blk) == 1) ? 2 : 3; \
    float v_ = (v); \
    if ((blk) == 1) v_ = SQC * v_; \
    else if ((blk) == 3) v_ = CC * fast_sigmoid(v_ + (bb)); \
    *(float*)(rowp + sub_ * 128 + (idx) * 4) = v_; \
}

// ---------- 256x256 TRI-buffer MFMA GEMM: A and B single fp16 ----------
// LDS: 3 buffers x 32KB = 96KB dynamic (1 block/CU, 8 waves = 2/SIMD).
// Counted-vmcnt pipeline (T4): stage tile t+2 at iter t; tile-top wait is
// vmcnt(4) -- tile t landed, tile t+1's 4 loads stay in flight ACROSS the
// barrier. Only the last tile drains to 0. Staging latency (~600-900cy)
// amortizes over 2 tile periods of MFMA.
__global__ __launch_bounds__(512, 1)
void gemm_mfma8(const char* __restrict__ Axp, const char* __restrict__ Wsp,
                float* __restrict__ C, const float* __restrict__ bias)
{
    extern __shared__ char ldsb[];   // 98304
    const int tid  = threadIdx.x;
    const int wave = tid >> 6, lane = tid & 63;
    const int wm = wave >> 2, wn = wave & 3;        // 2 x 4 waves
    const int d  = blockIdx.x;
    const int s  = d >> 3;
    const int mt = (d & 7) * 8 + (s >> 3);          // XCD (d&7) owns 8 mt
    const int nt = s & 7;
    const int m0 = mt * 256, n0 = nt * 256;

    f32x4 acc[8][4] = {};

    // staging (single layout, both operands): wave stages rows [wave*32,+32)
    const char* aT = Axp + (size_t)(m0 + wave * 32 + (lane >> 2)) * BSTRIDE + (lane & 3) * 16;
    const char* bT = Wsp + (size_t)(n0 + wave * 32 + (lane >> 2)) * BSTRIDE + (lane & 3) * 16;
    const int ldst = wave * 32 * 64;                // 2KB per wave region

    const int fl = lane & 15, fh = lane >> 4;
    const int sslot = (fh ^ (fl & 3)) * 16;

    // prologue: stage tile 0 -> buf0, tile 1 -> buf1
    #pragma unroll
    for (int pt = 0; pt < 2; ++pt) {
        char* L = ldsb + pt * 32768;
        #pragma unroll
        for (int g = 0; g < 2; ++g)
            __builtin_amdgcn_global_load_lds(
                (const __attribute__((address_space(1))) uint32_t*)(aT + pt * BROWB + (size_t)g * 16 * BSTRIDE),
                (__attribute__((address_space(3))) uint32_t*)(L + ldst + g * 1024),
                16, 0, 0);
        #pragma unroll
        for (int g = 0; g < 2; ++g)
            __builtin_amdgcn_global_load_lds(
                (const __attribute__((address_space(1))) uint32_t*)(bT + pt * BROWB + (size_t)g * 16 * BSTRIDE),
                (__attribute__((address_space(3))) uint32_t*)(L + 16384 + ldst + g * 1024),
                16, 0, 0);
    }

    union u8 { int4 i; h8_t h; };
    u8 Af[8], Bf[4];

    int cur = 0;                 // buf index of tile t
    for (int t = 0; t < KB_CNT; ++t) {
        char* Lc = ldsb + cur * 32768;
        int nxt2 = cur + 2; if (nxt2 >= 3) nxt2 -= 3;   // buf for tile t+2
        char* Ln = ldsb + nxt2 * 32768;
        const bool stg = (t + 2 < KB_CNT);

        // tile top: tile t landed (oldest 4 of the <=8 outstanding);
        // t+1's staging stays IN FLIGHT across the barrier.
        if (t + 1 < KB_CNT) {
            asm volatile("s_waitcnt vmcnt(4)" ::: "memory");
        } else {
            asm volatile("s_waitcnt vmcnt(0)" ::: "memory");
        }
        __builtin_amdgcn_s_barrier();
        asm volatile("" ::: "memory");

        // issue staging for tile t+2 (buffer freed: all waves finished t-1)
        if (stg) {
            const char* aN = aT + (t + 2) * BROWB;
            const char* bN = bT + (t + 2) * BROWB;
            #pragma unroll
            for (int g = 0; g < 2; ++g)
                __builtin_amdgcn_global_load_lds(
                    (const __attribute__((address_space(1))) uint32_t*)(aN + (size_t)g * 16 * BSTRIDE),
                    (__attribute__((address_space(3))) uint32_t*)(Ln + ldst + g * 1024),
                    16, 0, 0);
            #pragma unroll
            for (int g = 0; g < 2; ++g)
                __builtin_amdgcn_global_load_lds(
                    (const __attribute__((address_space(1))) uint32_t*)(bN + (size_t)g * 16 * BSTRIDE),
                    (__attribute__((address_space(3))) uint32_t*)(Ln + 16384 + ldst + g * 1024),
                    16, 0, 0);
        }

        // ---- fragments ----
        #pragma unroll
        for (int f = 0; f < 8; ++f) {
            const char* base = Lc + (wm * 128 + f * 16 + fl) * 64;
            Af[f].i = *(const int4*)(base + sslot);
        }
        #pragma unroll
        for (int f = 0; f < 4; ++f) {
            const char* base = Lc + 16384 + (wn * 64 + f * 16 + fl) * 64;
            Bf[f].i = *(const int4*)(base + sslot);
        }

        // ---- 32 MFMA: independent accumulators ----
        __builtin_amdgcn_s_setprio(1);
        #pragma unroll
        for (int i = 0; i < 8; ++i)
            #pragma unroll
            for (int j = 0; j < 4; ++j)
                acc[i][j] = __builtin_amdgcn_mfma_f32_16x16x32_f16(Af[i].h, Bf[j].h, acc[i][j], 0, 0, 0);
        __builtin_amdgcn_s_setprio(0);

        ++cur; if (cur >= 3) cur -= 3;
    }

    const int blk = nt >> 1;   // 0:k 1:v 2:q 3:beta
    if (blk == 0) {
        #pragma unroll
        for (int fm = 0; fm < 8; ++fm)
            #pragma unroll
            for (int hg = 0; hg < 2; ++hg)
                #pragma unroll
                for (int reg = 0; reg < 4; ++reg) {
                    float a = acc[fm][hg*2][reg], c = acc[fm][hg*2+1][reg];
                    float p = __builtin_fmaf(a, a, c * c);
                    p = reduce16(p);
                    float rn = SQC * frcp(fsqrt_(p) + 1e-6f);
                    acc[fm][hg*2][reg]   = a * rn;
                    acc[fm][hg*2+1][reg] = c * rn;
                }
    }

    #pragma unroll
    for (int fm = 0; fm < 8; ++fm) {
        int rbase = m0 + wm * 128 + fm * 16 + fh * 4;
        #pragma unroll
        for (int fn = 0; fn < 4; ++fn) {
            int col = n0 + wn * 64 + fn * 16 + fl;
            int hh  = (col >> 5) & 15;
            int idx = col & 31;
            float bb = (blk == 3) ? bias[col - 3 * HN] : 0.0f;
            #pragma unroll
            for (int reg = 0; reg < 4; ++reg) {
                float v = acc[fm][fn][reg];
                EPI_STORE(C, rbase, reg, hh, idx, blk, v, bb);
            }
        }
    }
}

// ---------- legacy 128x128 MFMA GEMM (fallback; A split in-kernel, B single) ----------
__global__ __launch_bounds__(256)
void gemm_mfma(const float* __restrict__ A, const char* __restrict__ Wsp,
               float* __restrict__ C, const float* __restrict__ bias)
{
    __shared__ char lds[24576];
    char* Asb = lds;            // 16KB split A
    char* Bsb = lds + 16384;    // 8KB single B

    const int tid  = threadIdx.x;
    const int wave = tid >> 6, lane = tid & 63;
    const int wm = wave >> 1, wn = wave & 1;
    const int nt = blockIdx.x & 15, mt = blockIdx.x >> 4;
    const int m0 = mt * 128, n0 = nt * 128;

    f32x4 acc[4][4] = {};

    const int ar = tid >> 1, akh = tid & 1, ars = ar & 7, ac0 = akh * 2;
    const float* asrc = A + (size_t)(m0 + ar) * DD + akh * 16;
    char* awr = Asb + ar * ROWB;

    const char* bsrc_base = Wsp + (size_t)n0 * BSTRIDE;

    const int fl = lane & 15, fh = lane >> 4;
    const int shiA = (fh ^ (fl & 7)) * 16;
    const int sloA = ((fh + 4) ^ (fl & 7)) * 16;
    const int shiB = (fh ^ (fl & 3)) * 16;

    for (int ks = 0; ks < KB_CNT; ++ks) {
        #pragma unroll
        for (int gg = 0; gg < 2; ++gg) {
            int g = wave * 2 + gg;
            const char* src = bsrc_base + (size_t)(g * 16 + (lane >> 2)) * BSTRIDE
                              + ks * BROWB + (lane & 3) * 16;
            __builtin_amdgcn_global_load_lds(
                (const __attribute__((address_space(1))) uint32_t*)src,
                (__attribute__((address_space(3))) uint32_t*)(Bsb + g * 1024),
                16, 0, 0);
        }
        {
            const float* ap = asrc + ks * 32;
            float f[16];
            *(float4*)&f[0]  = *(const float4*)(ap + 0);
            *(float4*)&f[4]  = *(const float4*)(ap + 4);
            *(float4*)&f[8]  = *(const float4*)(ap + 8);
            *(float4*)&f[12] = *(const float4*)(ap + 12);
            int4 hi0, hi1, lo0, lo1;
            split8(&f[0], hi0, lo0);
            split8(&f[8], hi1, lo1);
            *(int4*)(awr + (((ac0+0) ^ ars) * 16)) = hi0;
            *(int4*)(awr + (((ac0+1) ^ ars) * 16)) = hi1;
            *(int4*)(awr + (((ac0+4) ^ ars) * 16)) = lo0;
            *(int4*)(awr + (((ac0+5) ^ ars) * 16)) = lo1;
        }
        __syncthreads();

        union { int4 i; h8_t h; } ah[4], al[4], bf[4];
        #pragma unroll
        for (int fm = 0; fm < 4; ++fm) {
            const char* base = Asb + (wm * 64 + fm * 16 + fl) * ROWB;
            ah[fm].i = *(const int4*)(base + shiA);
            al[fm].i = *(const int4*)(base + sloA);
        }
        #pragma unroll
        for (int fn = 0; fn < 4; ++fn) {
            const char* base = Bsb + (wn * 64 + fn * 16 + fl) * BROWB;
            bf[fn].i = *(const int4*)(base + shiB);
        }
        #pragma unroll
        for (int fm = 0; fm < 4; ++fm)
            #pragma unroll
            for (int fn = 0; fn < 4; ++fn) {
                acc[fm][fn] = __builtin_amdgcn_mfma_f32_16x16x32_f16(ah[fm].h, bf[fn].h, acc[fm][fn], 0, 0, 0);
                acc[fm][fn] = __builtin_amdgcn_mfma_f32_16x16x32_f16(al[fm].h, bf[fn].h, acc[fm][fn], 0, 0, 0);
            }
        __syncthreads();
    }

    const int blk = nt >> 2;   // 0:k 1:v 2:q 3:beta
    if (blk == 0) {
        #pragma unroll
        for (int fm = 0; fm < 4; ++fm)
            #pragma unroll
            for (int hg = 0; hg < 2; ++hg)
                #pragma unroll
                for (int reg = 0; reg < 4; ++reg) {
                    float a = acc[fm][hg*2][reg], c = acc[fm][hg*2+1][reg];
                    float p = __builtin_fmaf(a, a, c * c);
                    p = reduce16(p);
                    float rn = SQC * frcp(fsqrt_(p) + 1e-6f);
                    acc[fm][hg*2][reg]   = a * rn;
                    acc[fm][hg*2+1][reg] = c * rn;
                }
    }

    #pragma unroll
    for (int fm = 0; fm < 4; ++fm) {
        int rbase = m0 + wm * 64 + fm * 16 + fh * 4;
        #pragma unroll
        for (int fn = 0; fn < 4; ++fn) {
            int col = n0 + wn * 64 + fn * 16 + fl;
            int hh  = (col >> 5) & 15;
            int idx = col & 31;
            float bb = (blk == 3) ? bias[col - 3 * HN] : 0.0f;
            #pragma unroll
            for (int reg = 0; reg < 4; ++reg) {
                float v = acc[fm][fn][reg];
                EPI_STORE(C, rbase, reg, hh, idx, blk, v, bb);
            }
        }
    }
}

// ---------- sequential recurrence (R9-proven 248us floor; do not touch) ----------
__global__ __launch_bounds__(256)
void recur(const float* __restrict__ proj, const float* __restrict__ S0,
           float* __restrict__ out, float* __restrict__ Sfin)
{
    const int tid = threadIdx.x;
    const int bx  = blockIdx.x;
    const int bh  = bx >> 1;                       // chain 0..127
    const int b   = bh >> 4, h = bh & 15;
    const int i   = ((bx & 1) << 4) + (tid >> 4);  // state row 0..31
    const int jl  = tid & 15;                      // owns j = 2jl, 2jl+1

    f32x2 S;
    {
        const float* s0p = S0 + (size_t)bh * 1024 + i * 32 + 2 * jl;
        S[0] = s0p[0]; S[1] = s0p[1];
    }

    const char* pkq = (const char*)proj + (size_t)b * 8192 + h * 512 + jl * 8;
    const char* pvb = (const char*)proj + (size_t)b * 8192 + h * 512 + 256 + i * 4;
    const size_t rstep = (size_t)BB * 8192;        // 65536 B per t

    f32x2 K2[PF], Q2[PF];
    float V[PF], Bt[PF];

    #pragma unroll
    for (int p = 0; p < PF; ++p) {
        asm volatile("global_load_dwordx2 %0, %1, off"            : "=v"(K2[p]) : "v"(pkq));
        asm volatile("global_load_dwordx2 %0, %1, off offset:128" : "=v"(Q2[p]) : "v"(pkq));
        asm volatile("global_load_dword %0, %1, off"              : "=v"(V[p])  : "v"(pvb));
        asm volatile("global_load_dword %0, %1, off offset:128"   : "=v"(Bt[p]) : "v"(pvb));
        pkq += rstep; pvb += rstep;
    }

    asm volatile("s_waitcnt vmcnt(28)" : "+v"(V[0]), "+v"(Bt[0]));
    float cv = V[0];
    f32x2 bS = Bt[0] * S;

    float* pout = out + (size_t)b * HN + h * 32 + i;   // stored when jl==0

    for (int t0 = 0; t0 < TT; t0 += PF) {
        float osave[PF];
        #pragma unroll
        for (int p = 0; p < PF; ++p) {
            const int pn = (p + 1) & (PF - 1);
            asm volatile("s_waitcnt vmcnt(24)"
                : "+v"(K2[p]), "+v"(Q2[p]), "+v"(V[pn]), "+v"(Bt[pn]));

            f32x2 k2 = K2[p];
            float rr = __builtin_fmaf(S[1], k2[1], S[0] * k2[0]);
            rr = reduce16(rr);
            float d = cv - rr;
            f32x2 a = d * k2 + bS;
            f32x2 e; e[0] = fexp2(a[0]); e[1] = fexp2(a[1]);
            f32x2 e1 = e + 1.0f;
            f32x2 r; r[0] = frcp(e1[0]); r[1] = frcp(e1[1]);
            S = -2.0f * r + 1.0f;

            f32x2 q2 = Q2[p];
            osave[p] = __builtin_fmaf(S[1], q2[1], S[0] * q2[0]);

            cv = V[pn];
            bS = Bt[pn] * S;

            asm volatile("global_load_dwordx2 %0, %1, off"            : "=v"(K2[p]) : "v"(pkq));
            asm volatile("global_load_dwordx2 %0, %1, off offset:128" : "=v"(Q2[p]) : "v"(pkq));
            asm volatile("global_load_dword %0, %1, off"              : "=v"(V[p])  : "v"(pvb));
            asm volatile("global_load_dword %0, %1, off offset:128"   : "=v"(Bt[p]) : "v"(pvb));
            pkq += rstep; pvb += rstep;
        }
        #pragma unroll
        for (int p = 0; p < PF; ++p) osave[p] = reduce16(osave[p]);
        if (jl == 0) {
            #pragma unroll
            for (int p = 0; p < PF; ++p) {
                float sq = osave[p];
                float sg = fast_sigmoid(sq);
                pout[(size_t)p * (BB * HN)] = sq * sq * sg;
            }
        }
        pout += (size_t)PF * (BB * HN);
    }

    {
        float* sf = Sfin + (size_t)bh * 1024 + i * 32 + 2 * jl;
        sf[0] = S[0]; sf[1] = S[1];
    }
}

extern "C" void kernel_launch(void* const* d_in, const int* in_sizes, int n_in,
                              void* d_out, int out_size, void* d_ws, size_t ws_size,
                              hipStream_t stream) {
    const float* x      = (const float*)d_in[0];
    const float* S0     = (const float*)d_in[1];
    const float* W_in   = (const float*)d_in[2];
    const float* W_k    = (const float*)d_in[3];
    const float* W_v    = (const float*)d_in[4];
    const float* W_q    = (const float*)d_in[5];
    const float* W_beta = (const float*)d_in[6];
    const float* b_beta = (const float*)d_in[7];

    float* ws   = (float*)d_ws;
    float* out_ = (float*)d_out;                  // [T,B,512]
    float* Sfin = out_ + (size_t)TT * BB * HN;    // [B,H,N,N]

    const size_t NEED_PRE = (size_t)(33554432 + 16777216 + 2*2097152) * 4; // 226.5 MB
    const bool pre = (ws_size >= NEED_PRE);

    if (pre) {
        float* proj   = ws;                         // 134 MB (packet layout)
        char*  xsplit = (char*)(ws + 33554432);     // 33.5 MB used (A single fp16)
        float* Weff   = ws + 33554432 + 16777216;   // 8 MB
        char*  wsplit = (char*)(Weff + 2097152);    // 4 MB (B single fp16)

        hipError_t aerr = hipFuncSetAttribute(
            reinterpret_cast<const void*>(&gemm_mfma8),
            hipFuncAttributeMaxDynamicSharedMemorySize, 98304);

        gemm_f32c<<<dim3(16, 32), dim3(256), 0, stream>>>(W_k, W_v, W_q, W_beta, W_in, Weff);
        wconv2<<<dim3(512), dim3(256), 0, stream>>>(Weff, wsplit);  // weights -> single fp16
        wconv2<<<dim3(4096), dim3(256), 0, stream>>>(x, xsplit);    // x -> single fp16
        if (aerr == hipSuccess) {
            gemm_mfma8<<<dim3(512), dim3(512), 98304, stream>>>(xsplit, wsplit, proj, b_beta);
        } else {
            gemm_mfma<<<dim3(2048), dim3(256), 0, stream>>>(x, wsplit, proj, b_beta);
        }
        recur<<<dim3(256), dim3(256), 0, stream>>>(proj, S0, out_, Sfin);
    } else {
        float* proj   = ws;
        float* Weff   = ws + 33554432;
        char*  wsplit = (char*)(Weff + 2097152);

        gemm_f32c<<<dim3(16, 32), dim3(256), 0, stream>>>(W_k, W_v, W_q, W_beta, W_in, Weff);
        wconv2<<<dim3(512), dim3(256), 0, stream>>>(Weff, wsplit);
        gemm_mfma<<<dim3(2048), dim3(256), 0, stream>>>(x, wsplit, proj, b_beta);
        recur<<<dim3(256), dim3(256), 0, stream>>>(proj, S0, out_, Sfin);
    }
}

// Round 21
// 424.545 us; speedup vs baseline: 1.0140x; 1.0140x over previous
//
#include <hip/hip_runtime.h>
#include <hip/hip_bf16.h>
#include <stdint.h>

#define TT 2048
#define BB 8
#define DD 1024
#define FF 2048   // 4*H*N
#define HN 512
#define KB_CNT 32         // DD/32 k-blocks
#define ROWB 128          // bytes per (row, k-block) in SPLIT layout (legacy A)
#define MSTRIDE 4096      // bytes per row, split layout
#define BROWB 64          // bytes per (row, k-block) in SINGLE-fp16 layout
#define BSTRIDE 2048      // bytes per row, single layout = KB_CNT*BROWB
#define PF 8              // recurrence pipeline depth (R9-proven floor)

typedef float f32x4 __attribute__((ext_vector_type(4)));
typedef float f32x2 __attribute__((ext_vector_type(2)));
typedef _Float16 h8_t __attribute__((ext_vector_type(8)));

#define CC   2.88539008f    // 2/ln2
#define SQC  1.69864360f    // sqrt(2/ln2)

// ---------- fast math helpers ----------
__device__ __forceinline__ float fexp2(float x){ return __builtin_amdgcn_exp2f(x); }
__device__ __forceinline__ float frcp(float x){ return __builtin_amdgcn_rcpf(x); }
__device__ __forceinline__ float fsqrt_(float x){ return __builtin_amdgcn_sqrtf(x); }
__device__ __forceinline__ float fast_sigmoid(float x){
    return frcp(1.0f + fexp2(-1.44269504f * x));
}

// DPP butterfly add
template<int CTRL>
__device__ __forceinline__ float dppadd(float v){
    int x = __builtin_amdgcn_update_dpp(0, __float_as_int(v), CTRL, 0xf, 0xf, true);
    return v + __int_as_float(x);
}
__device__ __forceinline__ float reduce16(float v){
    v = dppadd<0xB1>(v);   // + lane^1
    v = dppadd<0x4E>(v);   // + lane^2
    v = dppadd<0x141>(v);  // row_half_mirror: + lane^4
    v = dppadd<0x140>(v);  // row_mirror:      + lane^8
    return v;
}

// ---------- split fp32 -> (hi,lo) fp16 (legacy fallback) ----------
__device__ __forceinline__ void split8(const float* f, int4& hi, int4& lo){
    union { _Float16 h[8]; int4 i; } a, c;
    #pragma unroll
    for (int u = 0; u < 8; ++u) {
        _Float16 h = (_Float16)f[u];
        a.h[u] = h;
        c.h[u] = (_Float16)(f[u] - (float)h);
    }
    hi = a.i; lo = c.i;
}
// ---------- fp32 -> single fp16 (8 at a time) ----------
__device__ __forceinline__ int4 cvt8(const float* f){
    union { _Float16 h[8]; int4 i; } a;
    #pragma unroll
    for (int u = 0; u < 8; ++u) a.h[u] = (_Float16)f[u];
    return a.i;
}

// ---------- Weff = [Wk;Wv;Wq;Wb] * W_in, fused concat, 64x64 tiles ----------
// Epilogue writes SINGLE-fp16 pre-swizzled wsplit directly (no Weff buffer):
// row n, col group colb = n0+tx*4: kb = colb>>5, chunk c = (colb>>3)&3 at
// slot c^(n&3), 8B half chosen by (colb>>2)&1. Byte-disjoint across threads.
__global__ __launch_bounds__(256)
void gemm_f32cs(const float* __restrict__ s0, const float* __restrict__ s1,
                const float* __restrict__ s2, const float* __restrict__ s3,
                const float* __restrict__ B, char* __restrict__ outs)
{
    __shared__ __align__(16) float As[16][68];
    __shared__ __align__(16) float Bs[16][72];
    const int tid = threadIdx.x;
    const int tx = tid & 15, ty = tid >> 4;
    const int n0 = blockIdx.x * 64, m0 = blockIdx.y * 64;
    float acc[4][4] = {};

    const int arow = tid >> 2, ac4 = (tid & 3) << 2;
    const int f = m0 + arow;
    const float* asrc = ((f < 512) ? s0 : (f < 1024) ? s1 : (f < 1536) ? s2 : s3)
                        + (size_t)(f & 511) * DD + ac4;
    const int bk = tid >> 4, bc = tid & 15;

    for (int k0 = 0; k0 < DD; k0 += 16) {
        float4 av = *(const float4*)(asrc + k0);
        As[ac4+0][arow] = av.x; As[ac4+1][arow] = av.y;
        As[ac4+2][arow] = av.z; As[ac4+3][arow] = av.w;
        float4 bv = *(const float4*)&B[(size_t)(k0 + bk) * DD + n0 + bc * 4];
        int p = bc + (bc >> 3);
        *(float4*)&Bs[bk][p << 2] = bv;
        __syncthreads();
        #pragma unroll
        for (int kk = 0; kk < 16; ++kk) {
            float a[4], b[4];
            *(float4*)&a[0] = *(const float4*)&As[kk][ty * 4];
            int p2 = tx + (tx >> 3);
            *(float4*)&b[0] = *(const float4*)&Bs[kk][p2 << 2];
            #pragma unroll
            for (int i = 0; i < 4; ++i)
                #pragma unroll
                for (int j = 0; j < 4; ++j)
                    acc[i][j] = __builtin_fmaf(a[i], b[j], acc[i][j]);
        }
        __syncthreads();
    }
    const int colb = n0 + tx * 4;
    const int kb = colb >> 5;
    const int c  = (colb >> 3) & 3;
    const int halfsel = (colb >> 2) & 1;
    #pragma unroll
    for (int ii = 0; ii < 4; ++ii) {
        int n = m0 + ty * 4 + ii;
        int rs = n & 3;
        union { _Float16 h[4]; int2 i2; } pk;
        #pragma unroll
        for (int u = 0; u < 4; ++u) pk.h[u] = (_Float16)acc[ii][u];
        char* dst = outs + (size_t)n * BSTRIDE + kb * BROWB
                    + ((c ^ rs) * 16) + halfsel * 8;
        *(int2*)dst = pk.i2;
    }
}

// ---------- fp32 -> SINGLE fp16 pre-swizzled (x -> A operand) ----------
__global__ __launch_bounds__(256)
void wconv2(const float* __restrict__ W, char* __restrict__ out)
{
    int gid = blockIdx.x * 256 + threadIdx.x;
    int n  = gid >> 6;
    int kh = gid & 63;          // 16 floats per thread
    const float* src = W + (size_t)n * DD + kh * 16;
    float f[16];
    *(float4*)&f[0]  = *(const float4*)(src + 0);
    *(float4*)&f[4]  = *(const float4*)(src + 4);
    *(float4*)&f[8]  = *(const float4*)(src + 8);
    *(float4*)&f[12] = *(const float4*)(src + 12);
    int4 h0 = cvt8(&f[0]);
    int4 h1 = cvt8(&f[8]);
    int kb = kh >> 1, c0 = (kh & 1) * 2, rs = n & 3;
    char* dst = out + (size_t)n * BSTRIDE + kb * BROWB;
    *(int4*)(dst + (((c0+0) ^ rs) * 16)) = h0;
    *(int4*)(dst + (((c0+1) ^ rs) * 16)) = h1;
}

// Epilogue packet layout (8192B per row m, 512B per h), de-interleaved:
//   k@0 + idx*4, q@128 + idx*4, v~@256 + idx*4 (SQC*v), b~@384 + idx*4
#define EPI_STORE(Cb, rbase, reg, hh, idx, blk, v, bb) { \
    char* rowp = (char*)(Cb) + (size_t)((rbase) + (reg)) * 8192 + (hh) * 512; \
    int sub_ = ((blk) == 0) ? 0 : ((blk) == 2) ? 1 : ((blk) == 1) ? 2 : 3; \
    float v_ = (v); \
    if ((blk) == 1) v_ = SQC * v_; \
    else if ((blk) == 3) v_ = CC * fast_sigmoid(v_ + (bb)); \
    *(float*)(rowp + sub_ * 128 + (idx) * 4) = v_; \
}

// ---------- 256x256 TRI-buffer MFMA GEMM: A and B single fp16 (R17/R18) ----------
__global__ __launch_bounds__(512, 1)
void gemm_mfma8(const char* __restrict__ Axp, const char* __restrict__ Wsp,
                float* __restrict__ C, const float* __restrict__ bias)
{
    extern __shared__ char ldsb[];   // 98304
    const int tid  = threadIdx.x;
    const int wave = tid >> 6, lane = tid & 63;
    const int wm = wave >> 2, wn = wave & 3;        // 2 x 4 waves
    const int d  = blockIdx.x;
    const int s  = d >> 3;
    const int mt = (d & 7) * 8 + (s >> 3);          // XCD (d&7) owns 8 mt
    const int nt = s & 7;
    const int m0 = mt * 256, n0 = nt * 256;

    f32x4 acc[8][4] = {};

    const char* aT = Axp + (size_t)(m0 + wave * 32 + (lane >> 2)) * BSTRIDE + (lane & 3) * 16;
    const char* bT = Wsp + (size_t)(n0 + wave * 32 + (lane >> 2)) * BSTRIDE + (lane & 3) * 16;
    const int ldst = wave * 32 * 64;                // 2KB per wave region

    const int fl = lane & 15, fh = lane >> 4;
    const int sslot = (fh ^ (fl & 3)) * 16;

    // prologue: stage tile 0 -> buf0, tile 1 -> buf1
    #pragma unroll
    for (int pt = 0; pt < 2; ++pt) {
        char* L = ldsb + pt * 32768;
        #pragma unroll
        for (int g = 0; g < 2; ++g)
            __builtin_amdgcn_global_load_lds(
                (const __attribute__((address_space(1))) uint32_t*)(aT + pt * BROWB + (size_t)g * 16 * BSTRIDE),
                (__attribute__((address_space(3))) uint32_t*)(L + ldst + g * 1024),
                16, 0, 0);
        #pragma unroll
        for (int g = 0; g < 2; ++g)
            __builtin_amdgcn_global_load_lds(
                (const __attribute__((address_space(1))) uint32_t*)(bT + pt * BROWB + (size_t)g * 16 * BSTRIDE),
                (__attribute__((address_space(3))) uint32_t*)(L + 16384 + ldst + g * 1024),
                16, 0, 0);
    }

    union u8 { int4 i; h8_t h; };
    u8 Af[8], Bf[4];

    int cur = 0;
    for (int t = 0; t < KB_CNT; ++t) {
        char* Lc = ldsb + cur * 32768;
        int nxt2 = cur + 2; if (nxt2 >= 3) nxt2 -= 3;
        char* Ln = ldsb + nxt2 * 32768;
        const bool stg = (t + 2 < KB_CNT);

        if (t + 1 < KB_CNT) {
            asm volatile("s_waitcnt vmcnt(4)" ::: "memory");
        } else {
            asm volatile("s_waitcnt vmcnt(0)" ::: "memory");
        }
        __builtin_amdgcn_s_barrier();
        asm volatile("" ::: "memory");

        if (stg) {
            const char* aN = aT + (t + 2) * BROWB;
            const char* bN = bT + (t + 2) * BROWB;
            #pragma unroll
            for (int g = 0; g < 2; ++g)
                __builtin_amdgcn_global_load_lds(
                    (const __attribute__((address_space(1))) uint32_t*)(aN + (size_t)g * 16 * BSTRIDE),
                    (__attribute__((address_space(3))) uint32_t*)(Ln + ldst + g * 1024),
                    16, 0, 0);
            #pragma unroll
            for (int g = 0; g < 2; ++g)
                __builtin_amdgcn_global_load_lds(
                    (const __attribute__((address_space(1))) uint32_t*)(bN + (size_t)g * 16 * BSTRIDE),
                    (__attribute__((address_space(3))) uint32_t*)(Ln + 16384 + ldst + g * 1024),
                    16, 0, 0);
        }

        #pragma unroll
        for (int f = 0; f < 8; ++f) {
            const char* base = Lc + (wm * 128 + f * 16 + fl) * 64;
            Af[f].i = *(const int4*)(base + sslot);
        }
        #pragma unroll
        for (int f = 0; f < 4; ++f) {
            const char* base = Lc + 16384 + (wn * 64 + f * 16 + fl) * 64;
            Bf[f].i = *(const int4*)(base + sslot);
        }

        __builtin_amdgcn_s_setprio(1);
        #pragma unroll
        for (int i = 0; i < 8; ++i)
            #pragma unroll
            for (int j = 0; j < 4; ++j)
                acc[i][j] = __builtin_amdgcn_mfma_f32_16x16x32_f16(Af[i].h, Bf[j].h, acc[i][j], 0, 0, 0);
        __builtin_amdgcn_s_setprio(0);

        ++cur; if (cur >= 3) cur -= 3;
    }

    const int blk = nt >> 1;   // 0:k 1:v 2:q 3:beta
    if (blk == 0) {
        #pragma unroll
        for (int fm = 0; fm < 8; ++fm)
            #pragma unroll
            for (int hg = 0; hg < 2; ++hg)
                #pragma unroll
                for (int reg = 0; reg < 4; ++reg) {
                    float a = acc[fm][hg*2][reg], c = acc[fm][hg*2+1][reg];
                    float p = __builtin_fmaf(a, a, c * c);
                    p = reduce16(p);
                    float rn = SQC * frcp(fsqrt_(p) + 1e-6f);
                    acc[fm][hg*2][reg]   = a * rn;
                    acc[fm][hg*2+1][reg] = c * rn;
                }
    }

    #pragma unroll
    for (int fm = 0; fm < 8; ++fm) {
        int rbase = m0 + wm * 128 + fm * 16 + fh * 4;
        #pragma unroll
        for (int fn = 0; fn < 4; ++fn) {
            int col = n0 + wn * 64 + fn * 16 + fl;
            int hh  = (col >> 5) & 15;
            int idx = col & 31;
            float bb = (blk == 3) ? bias[col - 3 * HN] : 0.0f;
            #pragma unroll
            for (int reg = 0; reg < 4; ++reg) {
                float v = acc[fm][fn][reg];
                EPI_STORE(C, rbase, reg, hh, idx, blk, v, bb);
            }
        }
    }
}

// ---------- legacy 128x128 MFMA GEMM (fallback; A split in-kernel, B single) ----------
__global__ __launch_bounds__(256)
void gemm_mfma(const float* __restrict__ A, const char* __restrict__ Wsp,
               float* __restrict__ C, const float* __restrict__ bias)
{
    __shared__ char lds[24576];
    char* Asb = lds;
    char* Bsb = lds + 16384;

    const int tid  = threadIdx.x;
    const int wave = tid >> 6, lane = tid & 63;
    const int wm = wave >> 1, wn = wave & 1;
    const int nt = blockIdx.x & 15, mt = blockIdx.x >> 4;
    const int m0 = mt * 128, n0 = nt * 128;

    f32x4 acc[4][4] = {};

    const int ar = tid >> 1, akh = tid & 1, ars = ar & 7, ac0 = akh * 2;
    const float* asrc = A + (size_t)(m0 + ar) * DD + akh * 16;
    char* awr = Asb + ar * ROWB;

    const char* bsrc_base = Wsp + (size_t)n0 * BSTRIDE;

    const int fl = lane & 15, fh = lane >> 4;
    const int shiA = (fh ^ (fl & 7)) * 16;
    const int sloA = ((fh + 4) ^ (fl & 7)) * 16;
    const int shiB = (fh ^ (fl & 3)) * 16;

    for (int ks = 0; ks < KB_CNT; ++ks) {
        #pragma unroll
        for (int gg = 0; gg < 2; ++gg) {
            int g = wave * 2 + gg;
            const char* src = bsrc_base + (size_t)(g * 16 + (lane >> 2)) * BSTRIDE
                              + ks * BROWB + (lane & 3) * 16;
            __builtin_amdgcn_global_load_lds(
                (const __attribute__((address_space(1))) uint32_t*)src,
                (__attribute__((address_space(3))) uint32_t*)(Bsb + g * 1024),
                16, 0, 0);
        }
        {
            const float* ap = asrc + ks * 32;
            float f[16];
            *(float4*)&f[0]  = *(const float4*)(ap + 0);
            *(float4*)&f[4]  = *(const float4*)(ap + 4);
            *(float4*)&f[8]  = *(const float4*)(ap + 8);
            *(float4*)&f[12] = *(const float4*)(ap + 12);
            int4 hi0, hi1, lo0, lo1;
            split8(&f[0], hi0, lo0);
            split8(&f[8], hi1, lo1);
            *(int4*)(awr + (((ac0+0) ^ ars) * 16)) = hi0;
            *(int4*)(awr + (((ac0+1) ^ ars) * 16)) = hi1;
            *(int4*)(awr + (((ac0+4) ^ ars) * 16)) = lo0;
            *(int4*)(awr + (((ac0+5) ^ ars) * 16)) = lo1;
        }
        __syncthreads();

        union { int4 i; h8_t h; } ah[4], al[4], bf[4];
        #pragma unroll
        for (int fm = 0; fm < 4; ++fm) {
            const char* base = Asb + (wm * 64 + fm * 16 + fl) * ROWB;
            ah[fm].i = *(const int4*)(base + shiA);
            al[fm].i = *(const int4*)(base + sloA);
        }
        #pragma unroll
        for (int fn = 0; fn < 4; ++fn) {
            const char* base = Bsb + (wn * 64 + fn * 16 + fl) * BROWB;
            bf[fn].i = *(const int4*)(base + shiB);
        }
        #pragma unroll
        for (int fm = 0; fm < 4; ++fm)
            #pragma unroll
            for (int fn = 0; fn < 4; ++fn) {
                acc[fm][fn] = __builtin_amdgcn_mfma_f32_16x16x32_f16(ah[fm].h, bf[fn].h, acc[fm][fn], 0, 0, 0);
                acc[fm][fn] = __builtin_amdgcn_mfma_f32_16x16x32_f16(al[fm].h, bf[fn].h, acc[fm][fn], 0, 0, 0);
            }
        __syncthreads();
    }

    const int blk = nt >> 2;
    if (blk == 0) {
        #pragma unroll
        for (int fm = 0; fm < 4; ++fm)
            #pragma unroll
            for (int hg = 0; hg < 2; ++hg)
                #pragma unroll
                for (int reg = 0; reg < 4; ++reg) {
                    float a = acc[fm][hg*2][reg], c = acc[fm][hg*2+1][reg];
                    float p = __builtin_fmaf(a, a, c * c);
                    p = reduce16(p);
                    float rn = SQC * frcp(fsqrt_(p) + 1e-6f);
                    acc[fm][hg*2][reg]   = a * rn;
                    acc[fm][hg*2+1][reg] = c * rn;
                }
    }

    #pragma unroll
    for (int fm = 0; fm < 4; ++fm) {
        int rbase = m0 + wm * 64 + fm * 16 + fh * 4;
        #pragma unroll
        for (int fn = 0; fn < 4; ++fn) {
            int col = n0 + wn * 64 + fn * 16 + fl;
            int hh  = (col >> 5) & 15;
            int idx = col & 31;
            float bb = (blk == 3) ? bias[col - 3 * HN] : 0.0f;
            #pragma unroll
            for (int reg = 0; reg < 4; ++reg) {
                float v = acc[fm][fn][reg];
                EPI_STORE(C, rbase, reg, hh, idx, blk, v, bb);
            }
        }
    }
}

// ---------- sequential recurrence (R9/R16-R18 proven, 248us; do not touch) ----------
__global__ __launch_bounds__(256)
void recur(const float* __restrict__ proj, const float* __restrict__ S0,
           float* __restrict__ out, float* __restrict__ Sfin)
{
    const int tid = threadIdx.x;
    const int bx  = blockIdx.x;
    const int bh  = bx >> 1;                       // chain 0..127
    const int b   = bh >> 4, h = bh & 15;
    const int i   = ((bx & 1) << 4) + (tid >> 4);  // state row 0..31
    const int jl  = tid & 15;                      // owns j = 2jl, 2jl+1

    f32x2 S;
    {
        const float* s0p = S0 + (size_t)bh * 1024 + i * 32 + 2 * jl;
        S[0] = s0p[0]; S[1] = s0p[1];
    }

    const char* pkq = (const char*)proj + (size_t)b * 8192 + h * 512 + jl * 8;
    const char* pvb = (const char*)proj + (size_t)b * 8192 + h * 512 + 256 + i * 4;
    const size_t rstep = (size_t)BB * 8192;        // 65536 B per t

    f32x2 K2[PF], Q2[PF];
    float V[PF], Bt[PF];

    #pragma unroll
    for (int p = 0; p < PF; ++p) {
        asm volatile("global_load_dwordx2 %0, %1, off"            : "=v"(K2[p]) : "v"(pkq));
        asm volatile("global_load_dwordx2 %0, %1, off offset:128" : "=v"(Q2[p]) : "v"(pkq));
        asm volatile("global_load_dword %0, %1, off"              : "=v"(V[p])  : "v"(pvb));
        asm volatile("global_load_dword %0, %1, off offset:128"   : "=v"(Bt[p]) : "v"(pvb));
        pkq += rstep; pvb += rstep;
    }

    asm volatile("s_waitcnt vmcnt(28)" : "+v"(V[0]), "+v"(Bt[0]));
    float cv = V[0];
    f32x2 bS = Bt[0] * S;

    float* pout = out + (size_t)b * HN + h * 32 + i;   // stored when jl==0

    for (int t0 = 0; t0 < TT; t0 += PF) {
        float osave[PF];
        #pragma unroll
        for (int p = 0; p < PF; ++p) {
            const int pn = (p + 1) & (PF - 1);
            asm volatile("s_waitcnt vmcnt(24)"
                : "+v"(K2[p]), "+v"(Q2[p]), "+v"(V[pn]), "+v"(Bt[pn]));

            f32x2 k2 = K2[p];
            float rr = __builtin_fmaf(S[1], k2[1], S[0] * k2[0]);
            rr = reduce16(rr);
            float d = cv - rr;
            f32x2 a = d * k2 + bS;
            f32x2 e; e[0] = fexp2(a[0]); e[1] = fexp2(a[1]);
            f32x2 e1 = e + 1.0f;
            f32x2 r; r[0] = frcp(e1[0]); r[1] = frcp(e1[1]);
            S = -2.0f * r + 1.0f;

            f32x2 q2 = Q2[p];
            osave[p] = __builtin_fmaf(S[1], q2[1], S[0] * q2[0]);

            cv = V[pn];
            bS = Bt[pn] * S;

            asm volatile("global_load_dwordx2 %0, %1, off"            : "=v"(K2[p]) : "v"(pkq));
            asm volatile("global_load_dwordx2 %0, %1, off offset:128" : "=v"(Q2[p]) : "v"(pkq));
            asm volatile("global_load_dword %0, %1, off"              : "=v"(V[p])  : "v"(pvb));
            asm volatile("global_load_dword %0, %1, off offset:128"   : "=v"(Bt[p]) : "v"(pvb));
            pkq += rstep; pvb += rstep;
        }
        #pragma unroll
        for (int p = 0; p < PF; ++p) osave[p] = reduce16(osave[p]);
        if (jl == 0) {
            #pragma unroll
            for (int p = 0; p < PF; ++p) {
                float sq = osave[p];
                float sg = fast_sigmoid(sq);
                pout[(size_t)p * (BB * HN)] = sq * sq * sg;
            }
        }
        pout += (size_t)PF * (BB * HN);
    }

    {
        float* sf = Sfin + (size_t)bh * 1024 + i * 32 + 2 * jl;
        sf[0] = S[0]; sf[1] = S[1];
    }
}

extern "C" void kernel_launch(void* const* d_in, const int* in_sizes, int n_in,
                              void* d_out, int out_size, void* d_ws, size_t ws_size,
                              hipStream_t stream) {
    const float* x      = (const float*)d_in[0];
    const float* S0     = (const float*)d_in[1];
    const float* W_in   = (const float*)d_in[2];
    const float* W_k    = (const float*)d_in[3];
    const float* W_v    = (const float*)d_in[4];
    const float* W_q    = (const float*)d_in[5];
    const float* W_beta = (const float*)d_in[6];
    const float* b_beta = (const float*)d_in[7];

    float* ws   = (float*)d_ws;
    float* out_ = (float*)d_out;                  // [T,B,512]
    float* Sfin = out_ + (size_t)TT * BB * HN;    // [B,H,N,N]

    const size_t NEED_PRE = (size_t)(33554432 + 16777216 + 2*2097152) * 4; // 226.5 MB
    const bool pre = (ws_size >= NEED_PRE);

    if (pre) {
        float* proj   = ws;                         // 134 MB (packet layout)
        char*  xsplit = (char*)(ws + 33554432);     // 33.5 MB used (A single fp16)
        char*  wsplit = (char*)(ws + 33554432 + 16777216);  // 4 MB (B single fp16)

        hipError_t aerr = hipFuncSetAttribute(
            reinterpret_cast<const void*>(&gemm_mfma8),
            hipFuncAttributeMaxDynamicSharedMemorySize, 98304);

        gemm_f32cs<<<dim3(16, 32), dim3(256), 0, stream>>>(W_k, W_v, W_q, W_beta, W_in, wsplit);
        wconv2<<<dim3(4096), dim3(256), 0, stream>>>(x, xsplit);    // x -> single fp16
        if (aerr == hipSuccess) {
            gemm_mfma8<<<dim3(512), dim3(512), 98304, stream>>>(xsplit, wsplit, proj, b_beta);
        } else {
            gemm_mfma<<<dim3(2048), dim3(256), 0, stream>>>(x, wsplit, proj, b_beta);
        }
        recur<<<dim3(256), dim3(256), 0, stream>>>(proj, S0, out_, Sfin);
    } else {
        float* proj   = ws;
        char*  wsplit = (char*)(ws + 33554432);

        gemm_f32cs<<<dim3(16, 32), dim3(256), 0, stream>>>(W_k, W_v, W_q, W_beta, W_in, wsplit);
        gemm_mfma<<<dim3(2048), dim3(256), 0, stream>>>(x, wsplit, proj, b_beta);
        recur<<<dim3(256), dim3(256), 0, stream>>>(proj, S0, out_, Sfin);
    }
}